// Round 13
// baseline (945.541 us; speedup 1.0000x reference)
//
#include <hip/hip_runtime.h>

// GINE-GNN forward on MI355X. Round 13:
//  - eacvt: one-time coalesced fp32->f16 conversion of edge_attr (51MB);
//    agg gathers 32B f16 rows (was 64B fp32 + in-loop cvt: 272MB FETCH).
//  - node_gemm: 128-row tile, 8x4 micro-tile, (256,3) -> halves block count
//    and weight-staging overhead. finalize_stats takes nblk.

#define N_  100000
#define E_  1600000
#define G_  2000
#define SCAN_NB 196          // ceil(N / 512)
#define GB2 782              // ceil(N / 128)

typedef _Float16 half2v __attribute__((ext_vector_type(2)));

__device__ __forceinline__ float leaky_(float z) { return z >= 0.f ? z : 0.01f * z; }

__device__ __forceinline__ half2v u2h(unsigned u) {
    union { unsigned u; half2v h; } c; c.u = u; return c.h;
}

__device__ __forceinline__ float dot2_(half2v a, half2v b, float c) {
#if __has_builtin(__builtin_amdgcn_fdot2)
    return __builtin_amdgcn_fdot2(a, b, c, false);
#else
    return c + (float)a.x * (float)b.x + (float)a.y * (float)b.y;
#endif
}

// ---------------------------------------------------------------------------
// Counting sort of edges by dst: hist(+rank) -> scanA/B/C -> place-lite.
// ---------------------------------------------------------------------------
__global__ __launch_bounds__(256) void hist_rank_kernel(
    const int* __restrict__ dst, int* __restrict__ cnt, int* __restrict__ rank)
{
#pragma unroll 4
    for (int e = blockIdx.x * 256 + threadIdx.x; e < E_; e += gridDim.x * 256)
        rank[e] = atomicAdd(&cnt[dst[e]], 1);
}

__global__ __launch_bounds__(256) void scanA(
    const int* __restrict__ cnt, int* __restrict__ blocksum)
{
    __shared__ int s[256];
    const int t = threadIdx.x, b = blockIdx.x;
    const int i0 = (b * 256 + t) * 2;
    int v = 0;
    if (i0 < N_) v += cnt[i0];
    if (i0 + 1 < N_) v += cnt[i0 + 1];
    s[t] = v; __syncthreads();
    for (int o = 128; o > 0; o >>= 1) { if (t < o) s[t] += s[t + o]; __syncthreads(); }
    if (t == 0) blocksum[b] = s[0];
}

__global__ __launch_bounds__(256) void scanB(
    const int* __restrict__ blocksum, int* __restrict__ blockpref)
{
    __shared__ int s[256];
    const int t = threadIdx.x;
    int v = (t < SCAN_NB) ? blocksum[t] : 0;
    s[t] = v; __syncthreads();
    for (int o = 1; o < 256; o <<= 1) {
        int u = (t >= o) ? s[t - o] : 0;
        __syncthreads(); s[t] += u; __syncthreads();
    }
    blockpref[t] = s[t] - v;   // exclusive
}

__global__ __launch_bounds__(256) void scanC(
    const int* __restrict__ cnt, int* __restrict__ off,
    const int* __restrict__ blockpref)
{
    __shared__ int s[256];
    const int t = threadIdx.x, b = blockIdx.x;
    const int i0 = (b * 256 + t) * 2;
    int v0 = (i0 < N_) ? cnt[i0] : 0;
    int v1 = (i0 + 1 < N_) ? cnt[i0 + 1] : 0;
    int pv = v0 + v1;
    s[t] = pv; __syncthreads();
    for (int o = 1; o < 256; o <<= 1) {
        int u = (t >= o) ? s[t - o] : 0;
        __syncthreads(); s[t] += u; __syncthreads();
    }
    int run = blockpref[b] + s[t] - pv;
    if (i0 < N_) {
        off[i0] = run; run += v0;
        if (i0 + 1 < N_) off[i0 + 1] = run;
    }
    if (b == 0 && t == 0) off[N_] = E_;
}

// place-lite: se[off[dst]+rank] = (src, eid). One 8B store per edge.
__global__ __launch_bounds__(256) void place_kernel(
    const int* __restrict__ src, const int* __restrict__ dst,
    const int* __restrict__ rank, const int* __restrict__ off,
    int2* __restrict__ se)
{
#pragma unroll 4
    for (int e = blockIdx.x * 256 + threadIdx.x; e < E_; e += gridDim.x * 256) {
        const int p = off[dst[e]] + rank[e];
        se[p] = make_int2(src[e], e);
    }
}

// one-time coalesced fp32 -> f16 conversion of edge_attr (original order)
__global__ __launch_bounds__(256) void eacvt_kernel(
    const float* __restrict__ edge_attr, unsigned short* __restrict__ ea16)
{
    for (int i = blockIdx.x * 256 + threadIdx.x; i < E_ * 4; i += gridDim.x * 256) {
        float4 f = ((const float4*)edge_attr)[i];
        union { unsigned long long u; half2v h[2]; } cv;
        cv.h[0] = half2v{(_Float16)f.x, (_Float16)f.y};
        cv.h[1] = half2v{(_Float16)f.z, (_Float16)f.w};
        ((unsigned long long*)ea16)[i] = cv.u;
    }
}

// ---------------------------------------------------------------------------
// Sorted-edge aggregation: one wave owns DPW consecutive destinations.
// se chunk (coalesced int2) -> shfl eid -> 2 lanes/row gather 16B of the f16
// row -> LDS. Pipelined 2 chunks ahead. x gathers optionally BN+leaky inline.
// ---------------------------------------------------------------------------
#define DPW 13
#define CHUNK 32

template<int CI, int APPLY_BN>
__global__ __launch_bounds__(256, 4) void agg_sorted(
    const unsigned short* __restrict__ ea16,   // [E,16] f16, original order
    const int2* __restrict__ se,               // [E] (src,eid) sorted by dst
    const int* __restrict__ off,
    const float* __restrict__ We, const float* __restrict__ be,
    const float* __restrict__ x,               // raw x0 or pre-BN v
    const float* __restrict__ stIn,            // APPLY_BN: sums[128]
    const float* __restrict__ bng, const float* __restrict__ bnb,
    float* __restrict__ agg)
{
    __shared__ __align__(16) unsigned s_ea[4][2][CHUNK * 8];   // 8 KB (f16 rows)
    __shared__ int s_src[4][2][CHUNK];                         // 1 KB
    const int t = threadIdx.x;
    const int lane = t & 63;
    const int w = t >> 6;
    const int wid = __builtin_amdgcn_readfirstlane(blockIdx.x * 4 + w);

    half2v wh[8];
#pragma unroll
    for (int k = 0; k < 8; ++k) wh[k] = half2v{(_Float16)0.f, (_Float16)0.f};
    float beL = 0.f, scL = 1.f, shL = 0.f;
    if (lane < CI) {
#pragma unroll
        for (int k = 0; k < 8; ++k)
            wh[k] = half2v{(_Float16)We[(2 * k) * CI + lane],
                           (_Float16)We[(2 * k + 1) * CI + lane]};
        beL = be[lane];
        if (APPLY_BN) {
            float mean = stIn[lane] * (1.0f / N_);
            float var  = stIn[64 + lane] * (1.0f / N_) - mean * mean;
            scL = bng[lane] * rsqrtf(var + 1e-5f);
            shL = bnb[lane] - mean * scL;
        }
    }
    const int ln = (lane < CI) ? lane : 0;

    const int d0 = wid * DPW;
    if (d0 >= N_) return;
    const int d1 = min(d0 + DPW, N_);
    const int pw0 = off[d0];
    const int pw1 = off[d1];
    if (pw0 >= pw1) {   // all-empty range
        for (int d = d0; d < d1; ++d)
            if (lane < CI) agg[(size_t)d * CI + lane] = 0.f;
        return;
    }

    int d = d0;
    int e1 = off[d0 + 1];
    float acc = 0.f;
    int buf = 0;
    const int r = lane >> 1;            // row this lane gathers (2 lanes/row)
    const int hf = lane & 1;            // which 16B half of the 32B row

    // ---- prologue: stage chunk 0 (exposed once), load se for chunk 1 ----
    {
        const int m0 = min(CHUNK, pw1 - pw0);
        int2 t0 = make_int2(0, 0);
        if (lane < m0) t0 = se[pw0 + lane];
        int e = __shfl(t0.y, r);
        if (r >= m0) e = 0;
        uint4 v = ((const uint4*)(ea16 + (size_t)e * 16))[hf];
        *(uint4*)&s_ea[w][0][r * 8 + hf * 4] = v;
        if (lane < CHUNK) s_src[w][0][lane] = (lane < m0) ? t0.x : 0;
    }
    int2 pse = make_int2(0, 0);          // se for chunk n+1
    {
        const int np = pw0 + CHUNK;
        const int nm = min(CHUNK, pw1 - np);
        if (nm > 0 && lane < nm) pse = se[np + lane];
    }
    __builtin_amdgcn_wave_barrier();

    for (int cp = pw0; cp < pw1; cp += CHUNK) {
        const int m = min(CHUNK, pw1 - cp);
        const int np = cp + CHUNK;
        const int nm = min(CHUNK, pw1 - np);       // chunk n+1 size
        const int np2 = cp + 2 * CHUNK;
        const int nm2 = min(CHUNK, pw1 - np2);     // chunk n+2 size

        // (1) issue ea gather for chunk n+1 (pse resident) + se load for n+2
        uint4 g = make_uint4(0, 0, 0, 0);
        if (nm > 0) {
            int ge = __shfl(pse.y, r);
            if (r >= nm) ge = 0;
            g = ((const uint4*)(ea16 + (size_t)ge * 16))[hf];
        }
        int2 nse = make_int2(0, 0);
        if (nm2 > 0 && lane < nm2) nse = se[np2 + lane];

        // (2) x gathers + compute for chunk n
        float xr[CHUNK];
#pragma unroll
        for (int i = 0; i < CHUNK; ++i) {
            const int s = s_src[w][buf][i];           // broadcast ds_read
            float raw = x[(size_t)s * CI + ln];
            xr[i] = APPLY_BN ? leaky_(raw * scL + shL) : raw;
        }
#pragma unroll
        for (int i = 0; i < CHUNK; ++i) {
            if (i >= m) break;
            while (cp + i == e1) {
                if (lane < CI) agg[(size_t)d * CI + lane] = acc;
                acc = 0.f; ++d;
                e1 = off[d + 1];
            }
            const unsigned* er = &s_ea[w][buf][i * 8];
            uint4 e0 = *(const uint4*)&er[0];          // broadcast ds_read_b128
            uint4 e2 = *(const uint4*)&er[4];
            float dotv = beL;
            dotv = dot2_(u2h(e0.x), wh[0], dotv);
            dotv = dot2_(u2h(e0.y), wh[1], dotv);
            dotv = dot2_(u2h(e0.z), wh[2], dotv);
            dotv = dot2_(u2h(e0.w), wh[3], dotv);
            dotv = dot2_(u2h(e2.x), wh[4], dotv);
            dotv = dot2_(u2h(e2.y), wh[5], dotv);
            dotv = dot2_(u2h(e2.z), wh[6], dotv);
            dotv = dot2_(u2h(e2.w), wh[7], dotv);
            float mm = xr[i] + dotv;
            acc += (mm > 0.f ? mm : 0.f);
        }

        // (3) commit chunk n+1 to the alternate buffer, rotate se pipeline
        if (nm > 0) {
            *(uint4*)&s_ea[w][buf ^ 1][r * 8 + hf * 4] = g;
            if (lane < CHUNK) s_src[w][buf ^ 1][lane] = (lane < nm) ? pse.x : 0;
        }
        pse = nse;
        __builtin_amdgcn_wave_barrier();
        buf ^= 1;
    }

    // flush current dest + trailing zero-degree dests
    while (d < d1) {
        if (lane < CI) agg[(size_t)d * CI + lane] = acc;
        acc = 0.f; ++d;
    }
}

// ---------------------------------------------------------------------------
// Node GEMM, 128-row tile, 8x4 micro-tile. MODE 0: stage=(1+eps)*xin+agg,
// xin = BNIN ? leaky(BN(in)) : in. MODE 1: stage=leaky(BN1(u)).
// ---------------------------------------------------------------------------
template<int CI, int MODE, int BNIN>
__global__ __launch_bounds__(256, 3) void node_gemm(
    const float* __restrict__ in,
    const float* __restrict__ agg,   // MODE 0
    const float* __restrict__ eps,   // MODE 0
    const float* __restrict__ g1,
    const float* __restrict__ bt1,
    const float* __restrict__ stIn,
    const float* __restrict__ W, const float* __restrict__ bias_,
    float* __restrict__ outbuf, float* __restrict__ partial)
{
    __shared__ __align__(16) float a_lds[128][CI + 4];
    __shared__ __align__(16) float w_lds[CI][68];
    __shared__ float s_sc[64], s_sh[64];
    const int t = threadIdx.x;
    const int n0 = blockIdx.x * 128;
    constexpr int QR = CI / 4;

    if (MODE == 1 || BNIN) {
        if (t < 64) {
            float mean = stIn[t] * (1.0f / N_);
            float var  = stIn[64 + t] * (1.0f / N_) - mean * mean;
            float sc = g1[t] * rsqrtf(var + 1e-5f);
            s_sc[t] = sc;
            s_sh[t] = bt1[t] - mean * sc;
        }
        __syncthreads();
    }

    if (MODE == 0) {
        const float hs = 1.0f + eps[0];
        for (int f = t; f < 128 * QR; f += 256) {
            int i = f / QR, q = f - i * QR;
            int n = n0 + i;
            float4 val = make_float4(0.f, 0.f, 0.f, 0.f);
            if (n < N_) {
                float4 xa = *(const float4*)&in[(size_t)n * CI + q * 4];
                float4 ag = *(const float4*)&agg[(size_t)n * CI + q * 4];
                if (BNIN) {
                    int c = q * 4;
                    xa.x = leaky_(xa.x * s_sc[c]     + s_sh[c]);
                    xa.y = leaky_(xa.y * s_sc[c + 1] + s_sh[c + 1]);
                    xa.z = leaky_(xa.z * s_sc[c + 2] + s_sh[c + 2]);
                    xa.w = leaky_(xa.w * s_sc[c + 3] + s_sh[c + 3]);
                }
                val = make_float4(hs * xa.x + ag.x, hs * xa.y + ag.y,
                                  hs * xa.z + ag.z, hs * xa.w + ag.w);
            }
            *(float4*)&a_lds[i][q * 4] = val;
        }
    } else {
        for (int f = t; f < 128 * QR; f += 256) {
            int i = f / QR, q = f - i * QR;
            int n = n0 + i;
            float4 val = make_float4(0.f, 0.f, 0.f, 0.f);
            if (n < N_) {
                float4 uv = *(const float4*)&in[(size_t)n * CI + q * 4];
                int c = q * 4;
                val = make_float4(leaky_(uv.x * s_sc[c]     + s_sh[c]),
                                  leaky_(uv.y * s_sc[c + 1] + s_sh[c + 1]),
                                  leaky_(uv.z * s_sc[c + 2] + s_sh[c + 2]),
                                  leaky_(uv.w * s_sc[c + 3] + s_sh[c + 3]));
            }
            *(float4*)&a_lds[i][q * 4] = val;
        }
    }
    for (int f = t; f < CI * 16; f += 256) {
        int k = f >> 4, cq = f & 15;
        *(float4*)&w_lds[k][cq * 4] = *(const float4*)&W[k * 64 + cq * 4];
    }
    __syncthreads();

    const int tr = t & 15;           // rows: tr + 16*j, j<8
    const int c0 = (t >> 4) * 4;
    float acc[8][4] = {};
#pragma unroll 2
    for (int k = 0; k < CI; k += 4) {
        float ar[8][4];
#pragma unroll
        for (int j = 0; j < 8; ++j)
            *(float4*)&ar[j][0] = *(const float4*)&a_lds[tr + 16 * j][k];
#pragma unroll
        for (int kk = 0; kk < 4; ++kk) {
            float4 b = *(const float4*)&w_lds[k + kk][c0];
#pragma unroll
            for (int j = 0; j < 8; ++j) {
                acc[j][0] += ar[j][kk] * b.x;
                acc[j][1] += ar[j][kk] * b.y;
                acc[j][2] += ar[j][kk] * b.z;
                acc[j][3] += ar[j][kk] * b.w;
            }
        }
    }

    const float4 bb = *(const float4*)&bias_[c0];
    const float bias[4] = { bb.x, bb.y, bb.z, bb.w };
    float ls[4] = {}, lq[4] = {};
#pragma unroll
    for (int j = 0; j < 8; ++j) {
        int n = n0 + tr + 16 * j;
        if (n < N_) {
            float o[4];
#pragma unroll
            for (int cc = 0; cc < 4; ++cc) {
                o[cc] = acc[j][cc] + bias[cc];
                ls[cc] += o[cc];
                lq[cc] += o[cc] * o[cc];
            }
            *(float4*)&outbuf[(size_t)n * 64 + c0] = make_float4(o[0], o[1], o[2], o[3]);
        }
    }
#pragma unroll
    for (int m = 1; m <= 8; m <<= 1) {
#pragma unroll
        for (int cc = 0; cc < 4; ++cc) {
            ls[cc] += __shfl_xor(ls[cc], m);
            lq[cc] += __shfl_xor(lq[cc], m);
        }
    }
    if (tr == 0) {
#pragma unroll
        for (int cc = 0; cc < 4; ++cc) {
            partial[(size_t)(c0 + cc) * GB2 + blockIdx.x]      = ls[cc];
            partial[(size_t)(64 + c0 + cc) * GB2 + blockIdx.x] = lq[cc];
        }
    }
}

__global__ __launch_bounds__(256) void finalize_stats(
    const float* __restrict__ partial, float* __restrict__ stats)
{
    const int c = blockIdx.x;
    const int t = threadIdx.x;
    float s = 0.f;
    for (int b = t; b < GB2; b += 256) s += partial[(size_t)c * GB2 + b];
    __shared__ float red[256];
    red[t] = s; __syncthreads();
    for (int o = 128; o > 0; o >>= 1) { if (t < o) red[t] += red[t + o]; __syncthreads(); }
    if (t == 0) stats[c] = red[0];
}

// ---------------------------------------------------------------------------
// Pool with fused BN+leaky: pool[g] = sum_j leaky(BN(v[g*50+j])).
// ---------------------------------------------------------------------------
__global__ __launch_bounds__(256) void pool_kernel(
    const float* __restrict__ v, const float* __restrict__ st,
    const float* __restrict__ bg, const float* __restrict__ bb,
    float* __restrict__ pool)
{
    const int c = threadIdx.x & 63;
    const int g = blockIdx.x * 4 + (threadIdx.x >> 6);
    float mean = st[c] * (1.0f / N_);
    float var  = st[64 + c] * (1.0f / N_) - mean * mean;
    float sc = bg[c] * rsqrtf(var + 1e-5f);
    float sh = bb[c] - mean * sc;
    const float* p = v + (size_t)g * 50 * 64 + c;
    float s = 0.f;
#pragma unroll
    for (int j = 0; j < 50; ++j) s += leaky_(p[(size_t)j * 64] * sc + sh);
    pool[(size_t)g * 64 + c] = s;
}

// g0[g][c] = pool[g] @ W0b + b0  (W0b = W0 rows 64..127). 2 graphs/block.
__global__ __launch_bounds__(256) void pool_mlp0(
    const float* __restrict__ pool, const float* __restrict__ W0,
    const float* __restrict__ b0, float* __restrict__ g0)
{
    const int t = threadIdx.x;
    const int g = blockIdx.x * 2 + (t >> 7);
    const int c = t & 127;
    float s = b0[c];
    const float* pr = pool + (size_t)g * 64;
#pragma unroll 4
    for (int k = 0; k < 64; ++k)
        s += pr[k] * W0[(size_t)(64 + k) * 128 + c];
    g0[(size_t)g * 128 + c] = s;
}

// ---------------------------------------------------------------------------
// Fused MLP head, BN+leaky applied when staging v.
// ---------------------------------------------------------------------------
__global__ __launch_bounds__(256, 2) void mlp_kernel(
    const float* __restrict__ v, const float* __restrict__ st,
    const float* __restrict__ bg, const float* __restrict__ bb,
    const float* __restrict__ g0,
    const float* __restrict__ W0,
    const float* __restrict__ W1, const float* __restrict__ b1,
    const float* __restrict__ Wf, const float* __restrict__ bf,
    float* __restrict__ out)
{
    __shared__ __align__(16) float a_lds[128][132];   // 67.6 KB
    __shared__ __align__(16) float w_lds[16][132];    // 8.4 KB
    __shared__ __align__(16) float sWfT[2][128];
    __shared__ float s_scm[64], s_shm[64];
    __shared__ int sbid[128];
    const int t = threadIdx.x;
    const int n0 = blockIdx.x * 128;

    if (t < 64) {
        float mean = st[t] * (1.0f / N_);
        float var  = st[64 + t] * (1.0f / N_) - mean * mean;
        float sc = bg[t] * rsqrtf(var + 1e-5f);
        s_scm[t] = sc;
        s_shm[t] = bb[t] - mean * sc;
    }
    __syncthreads();

    for (int f = t; f < 128 * 16; f += 256) {
        int i = f >> 4, q = f & 15;
        int n = n0 + i;
        float4 val = make_float4(0.f, 0.f, 0.f, 0.f);
        if (n < N_) {
            float4 xv = *(const float4*)&v[(size_t)n * 64 + q * 4];
            int c = q * 4;
            val = make_float4(leaky_(xv.x * s_scm[c]     + s_shm[c]),
                              leaky_(xv.y * s_scm[c + 1] + s_shm[c + 1]),
                              leaky_(xv.z * s_scm[c + 2] + s_shm[c + 2]),
                              leaky_(xv.w * s_scm[c + 3] + s_shm[c + 3]));
        }
        *(float4*)&a_lds[i][q * 4] = val;
    }
    if (t < 128) {
        int n = n0 + t;
        sbid[t] = (n < N_) ? (n / 50) : (G_ - 1);
        sWfT[0][t] = Wf[t * 2];
        sWfT[1][t] = Wf[t * 2 + 1];
    }

    const int tr = t & 15;
    const int c0 = (t >> 4) * 8;
    float acc[8][8];

#pragma unroll
    for (int j = 0; j < 8; ++j)
#pragma unroll
        for (int cc = 0; cc < 8; ++cc) acc[j][cc] = 0.f;

    for (int kc = 0; kc < 64; kc += 16) {
        __syncthreads();
        for (int f = t; f < 16 * 32; f += 256) {
            int k = f >> 5, cq = f & 31;
            *(float4*)&w_lds[k][cq * 4] = *(const float4*)&W0[(size_t)(kc + k) * 128 + cq * 4];
        }
        __syncthreads();
        for (int k = 0; k < 16; k += 4) {
            float ar[8][4];
#pragma unroll
            for (int j = 0; j < 8; ++j)
                *(float4*)&ar[j][0] = *(const float4*)&a_lds[tr + 16 * j][kc + k];
#pragma unroll
            for (int kk = 0; kk < 4; ++kk) {
                float4 bA = *(const float4*)&w_lds[k + kk][c0];
                float4 bB = *(const float4*)&w_lds[k + kk][c0 + 4];
#pragma unroll
                for (int j = 0; j < 8; ++j) {
                    acc[j][0] += ar[j][kk] * bA.x;
                    acc[j][1] += ar[j][kk] * bA.y;
                    acc[j][2] += ar[j][kk] * bA.z;
                    acc[j][3] += ar[j][kk] * bA.w;
                    acc[j][4] += ar[j][kk] * bB.x;
                    acc[j][5] += ar[j][kk] * bB.y;
                    acc[j][6] += ar[j][kk] * bB.z;
                    acc[j][7] += ar[j][kk] * bB.w;
                }
            }
        }
    }
    __syncthreads();
#pragma unroll
    for (int j = 0; j < 8; ++j) {
        int row = tr + 16 * j;
        const float* gr = g0 + (size_t)sbid[row] * 128;
        float4 gA = *(const float4*)&gr[c0];
        float4 gB = *(const float4*)&gr[c0 + 4];
        float o[8] = { acc[j][0] + gA.x, acc[j][1] + gA.y, acc[j][2] + gA.z, acc[j][3] + gA.w,
                       acc[j][4] + gB.x, acc[j][5] + gB.y, acc[j][6] + gB.z, acc[j][7] + gB.w };
#pragma unroll
        for (int cc = 0; cc < 8; ++cc) o[cc] = leaky_(o[cc]);
        *(float4*)&a_lds[row][c0]     = make_float4(o[0], o[1], o[2], o[3]);
        *(float4*)&a_lds[row][c0 + 4] = make_float4(o[4], o[5], o[6], o[7]);
    }

#pragma unroll
    for (int j = 0; j < 8; ++j)
#pragma unroll
        for (int cc = 0; cc < 8; ++cc) acc[j][cc] = 0.f;

    for (int kc = 0; kc < 128; kc += 16) {
        __syncthreads();
        for (int f = t; f < 16 * 32; f += 256) {
            int k = f >> 5, cq = f & 31;
            *(float4*)&w_lds[k][cq * 4] = *(const float4*)&W1[(size_t)(kc + k) * 128 + cq * 4];
        }
        __syncthreads();
        for (int k = 0; k < 16; k += 4) {
            float ar[8][4];
#pragma unroll
            for (int j = 0; j < 8; ++j)
                *(float4*)&ar[j][0] = *(const float4*)&a_lds[tr + 16 * j][kc + k];
#pragma unroll
            for (int kk = 0; kk < 4; ++kk) {
                float4 bA = *(const float4*)&w_lds[k + kk][c0];
                float4 bB = *(const float4*)&w_lds[k + kk][c0 + 4];
#pragma unroll
                for (int j = 0; j < 8; ++j) {
                    acc[j][0] += ar[j][kk] * bA.x;
                    acc[j][1] += ar[j][kk] * bA.y;
                    acc[j][2] += ar[j][kk] * bA.z;
                    acc[j][3] += ar[j][kk] * bA.w;
                    acc[j][4] += ar[j][kk] * bB.x;
                    acc[j][5] += ar[j][kk] * bB.y;
                    acc[j][6] += ar[j][kk] * bB.z;
                    acc[j][7] += ar[j][kk] * bB.w;
                }
            }
        }
    }
    __syncthreads();
    {
        float4 bb0 = *(const float4*)&b1[c0];
        float4 bb1 = *(const float4*)&b1[c0 + 4];
        float bias[8] = { bb0.x, bb0.y, bb0.z, bb0.w, bb1.x, bb1.y, bb1.z, bb1.w };
#pragma unroll
        for (int j = 0; j < 8; ++j) {
            int row = tr + 16 * j;
            float o[8];
#pragma unroll
            for (int cc = 0; cc < 8; ++cc) o[cc] = leaky_(acc[j][cc] + bias[cc]);
            *(float4*)&a_lds[row][c0]     = make_float4(o[0], o[1], o[2], o[3]);
            *(float4*)&a_lds[row][c0 + 4] = make_float4(o[4], o[5], o[6], o[7]);
        }
    }
    __syncthreads();

    {
        int i = t >> 1, c = t & 1;
        int n = n0 + i;
        if (n < N_) {
            float s = bf[c];
            for (int k = 0; k < 128; k += 4) {
                float4 av = *(const float4*)&a_lds[i][k];
                float4 wv = *(const float4*)&sWfT[c][k];
                s += av.x * wv.x + av.y * wv.y + av.z * wv.z + av.w * wv.w;
            }
            out[(size_t)n * 2 + c] = s;
        }
    }
}

// ---------------------------------------------------------------------------
extern "C" void kernel_launch(void* const* d_in, const int* in_sizes, int n_in,
                              void* d_out, int out_size, void* d_ws, size_t ws_size,
                              hipStream_t stream)
{
    (void)in_sizes; (void)n_in; (void)out_size; (void)ws_size;

    const float* x0    = (const float*)d_in[0];
    const int*   eidx  = (const int*)d_in[1];
    const float* eattr = (const float*)d_in[2];
    const float* L[3][11];
    for (int l = 0; l < 3; ++l)
        for (int j = 0; j < 11; ++j)
            L[l][j] = (const float*)d_in[4 + l * 11 + j];
    const float* mlp0W = (const float*)d_in[37];
    const float* mlp0b = (const float*)d_in[38];
    const float* mlp1W = (const float*)d_in[39];
    const float* mlp1b = (const float*)d_in[40];
    const float* finW  = (const float*)d_in[41];
    const float* finb  = (const float*)d_in[42];
    float* out = (float*)d_out;

    float* ws    = (float*)d_ws;
    float* P0    = ws;                          // N*64 (agg)
    float* P1    = P0 + (size_t)N_ * 64;        // N*64 (u)
    float* P2    = P1 + (size_t)N_ * 64;        // N*64 (v, pre-BN)
    float* pool  = P2 + (size_t)N_ * 64;        // G*64
    float* g0    = pool + (size_t)G_ * 64;      // G*128
    float* stats = g0   + (size_t)G_ * 128;     // 768
    float* partial = stats + 768;               // 128*GB2
    int*   off   = (int*)(partial + 128 * GB2); // N+1 (+1 pad)
    int*   cnt   = off + (N_ + 2);              // N
    int*   bsum  = cnt + N_;                    // 256
    int*   bpref = bsum + 256;                  // 256
    int*   rank  = bpref + 256;                 // E
    int2*  se    = (int2*)(rank + E_);          // E (8B aligned)
    unsigned short* ea16 = (unsigned short*)(se + E_);  // E*16 f16

    const int* src = eidx;
    const int* dst = eidx + E_;

    // ---- counting sort of edges by dst + one-time f16 edge_attr ----
    hipMemsetAsync(cnt, 0, (size_t)N_ * sizeof(int), stream);
    hist_rank_kernel<<<2048, 256, 0, stream>>>(dst, cnt, rank);
    eacvt_kernel<<<2048, 256, 0, stream>>>(eattr, ea16);
    scanA<<<SCAN_NB, 256, 0, stream>>>(cnt, bsum);
    scanB<<<1, 256, 0, stream>>>(bsum, bpref);
    scanC<<<SCAN_NB, 256, 0, stream>>>(cnt, off, bpref);
    place_kernel<<<2048, 256, 0, stream>>>(src, dst, rank, off, se);

    const int AGGB = ((N_ + DPW - 1) / DPW + 3) / 4 + 1;

    for (int l = 0; l < 3; ++l) {
        float* s1 = stats + (2 * l) * 128;
        float* s2 = stats + (2 * l + 1) * 128;
        if (l == 0) {
            agg_sorted<40, 0><<<AGGB, 256, 0, stream>>>(ea16, se, off, L[0][1], L[0][2],
                                                        x0, nullptr, nullptr, nullptr, P0);
            node_gemm<40, 0, 0><<<GB2, 256, 0, stream>>>(x0, P0, L[0][0], nullptr, nullptr, nullptr,
                                                         L[0][3], L[0][4], P1, partial);
        } else {
            float* sp = stats + (2 * l - 1) * 128;   // prev layer outer stats
            agg_sorted<64, 1><<<AGGB, 256, 0, stream>>>(ea16, se, off, L[l][1], L[l][2],
                                                        P2, sp, L[l - 1][9], L[l - 1][10], P0);
            node_gemm<64, 0, 1><<<GB2, 256, 0, stream>>>(P2, P0, L[l][0], L[l - 1][9], L[l - 1][10], sp,
                                                         L[l][3], L[l][4], P1, partial);
        }
        finalize_stats<<<128, 256, 0, stream>>>(partial, s1);
        node_gemm<64, 1, 0><<<GB2, 256, 0, stream>>>(P1, nullptr, nullptr, L[l][5], L[l][6], s1,
                                                     L[l][7], L[l][8], P2, partial);
        finalize_stats<<<128, 256, 0, stream>>>(partial, s2);
    }

    // ---- pool + per-graph mlp0 term + fused MLP head (BN applied inline) ----
    float* sF = stats + 5 * 128;
    pool_kernel<<<G_ / 4, 256, 0, stream>>>(P2, sF, L[2][9], L[2][10], pool);
    pool_mlp0<<<G_ / 2, 256, 0, stream>>>(pool, mlp0W, mlp0b, g0);
    mlp_kernel<<<(N_ + 127) / 128, 256, 0, stream>>>(P2, sF, L[2][9], L[2][10], g0, mlp0W,
                                                     mlp1W, mlp1b, finW, finb, out);
}